// Round 3
// baseline (955.025 us; speedup 1.0000x reference)
//
#include <hip/hip_runtime.h>

// ---------------------------------------------------------------------------
// Routed top-2 MoE for MI355X (gfx950).  Round 3:
//  - gemm1/gemm2 rebuilt as 256-row tiles, 512 threads / 8 waves, BK=64,
//    2-phase double-buffered LDS (m230/m248-verified regime: MFMA wall per
//    K-tile ~2048 cy >> 900 cy HBM latency, so the barrier drain is hidden)
//  - gemm2: 256x256 (acc 8x4, ~210 VGPR); gemm1: 256x128 (two accs fit)
//  - 256-row tile map (<=80 tiles), chunk-local hbuf indexing (r2 bug fix)
//  - general bijective XCD swizzle (nwg not necessarily %8)
// ---------------------------------------------------------------------------

#define DEV static __device__ __forceinline__

typedef float  f32x4  __attribute__((ext_vector_type(4)));
typedef __bf16 bf16x8 __attribute__((ext_vector_type(8)));

DEV unsigned short f2bf(float f) {
  union { float f; unsigned u; } v; v.f = f;
  unsigned r = v.u + 0x7fffu + ((v.u >> 16) & 1u);   // RNE
  return (unsigned short)(r >> 16);
}
DEV float bf2f(unsigned short b) {
  union { unsigned u; float f; } v; v.u = ((unsigned)b) << 16;
  return v.f;
}

DEV void gll16(const void* g, void* l) {
  __builtin_amdgcn_global_load_lds(
      (const __attribute__((address_space(1))) unsigned int*)g,
      (__attribute__((address_space(3))) unsigned int*)l, 16, 0, 0);
}

DEV f32x4 mfma16(bf16x8 a, bf16x8 b, f32x4 c) {
  return __builtin_amdgcn_mfma_f32_16x16x32_bf16(a, b, c, 0, 0, 0);
}

// Bijective XCD chunk swizzle (m204 general form).
DEV int xcd_swz_gen(int bid, int nwg) {
  int x = bid & 7, o = bid >> 3;
  int q = nwg >> 3, r = nwg & 7;
  return (x < r ? x * (q + 1) : r * (q + 1) + (x - r) * q) + o;
}

// Read one bf16x8 fragment (row, k in [kb, kb+8)) from a swizzled tile.
DEV bf16x8 frag_read(const unsigned short* lds, int row, int kb) {
  int off = row * 128 + ((kb * 2) ^ ((row & 7) << 4));
  return *(const bf16x8*)((const char*)lds + off);
}

// ---- 256-thread staging (route gemm) --------------------------------------
DEV void stage_linear(const unsigned short* base, size_t pitch, int k0,
                      unsigned short* lds, int tid) {
  int wq = tid >> 6, lane = tid & 63;
#pragma unroll
  for (int i = 0; i < 4; ++i) {
    int s = wq * 256 + i * 64 + lane;     // 16B slot id, 1024 slots total
    int row = s >> 3, b = s & 7;
    int bb = b ^ (row & 7);
    const unsigned short* g = base + (size_t)row * pitch + (size_t)(k0 + bb * 8);
    gll16(g, lds + (size_t)(wq * 256 + i * 64) * 8);
  }
}

// ---- 512-thread staging (gemm1/gemm2) -------------------------------------
// [256][64] tile, 2048 slots, 4 per thread.
DEV void stage_l256(const unsigned short* base, size_t pitch, int k0,
                    unsigned short* lds, int tid) {
  int wq = tid >> 6, lane = tid & 63;
#pragma unroll
  for (int i = 0; i < 4; ++i) {
    int sb = wq * 256 + i * 64;
    int s = sb + lane;
    int row = s >> 3, b = s & 7;
    int bb = b ^ (row & 7);
    gll16(base + (size_t)row * pitch + (size_t)(k0 + bb * 8),
          lds + (size_t)sb * 8);
  }
}
DEV void stage_g256(const unsigned short* base, size_t pitch, size_t colOff,
                    int k0, const int* toks, unsigned short* lds, int tid) {
  int wq = tid >> 6, lane = tid & 63;
#pragma unroll
  for (int i = 0; i < 4; ++i) {
    int sb = wq * 256 + i * 64;
    int s = sb + lane;
    int row = s >> 3, b = s & 7;
    int bb = b ^ (row & 7);
    gll16(base + (size_t)toks[row] * pitch + colOff + (size_t)(k0 + bb * 8),
          lds + (size_t)sb * 8);
  }
}
// [128][64] tile, 1024 slots, 2 per thread.
DEV void stage_l128(const unsigned short* base, size_t pitch, int k0,
                    unsigned short* lds, int tid) {
  int wq = tid >> 6, lane = tid & 63;
#pragma unroll
  for (int i = 0; i < 2; ++i) {
    int sb = wq * 128 + i * 64;
    int s = sb + lane;
    int row = s >> 3, b = s & 7;
    int bb = b ^ (row & 7);
    gll16(base + (size_t)row * pitch + (size_t)(k0 + bb * 8),
          lds + (size_t)sb * 8);
  }
}

// ---- MFMA blocks ----------------------------------------------------------
// route gemm: 4 waves, per-wave 64x64 (acc 4x4)
DEV void mfma_block(const unsigned short* A, const unsigned short* B,
                    f32x4 (&acc)[4][4], int wm, int wn, int lg, int lc) {
#pragma unroll
  for (int ks = 0; ks < 2; ++ks) {
    int kb = ks * 32 + lg * 8;
    bf16x8 af[4], bff[4];
#pragma unroll
    for (int i = 0; i < 4; ++i) {
      af[i]  = frag_read(A, wm * 64 + i * 16 + lc, kb);
      bff[i] = frag_read(B, wn * 64 + i * 16 + lc, kb);
    }
#pragma unroll
    for (int mf = 0; mf < 4; ++mf)
#pragma unroll
      for (int nf = 0; nf < 4; ++nf)
        acc[mf][nf] = mfma16(af[mf], bff[nf], acc[mf][nf]);
  }
}
// gemm2: 8 waves (2Mx4N), per-wave 128x64 (acc 8x4)
DEV void mfma256x256(const unsigned short* A, const unsigned short* B,
                     f32x4 (&acc)[8][4], int wm, int wn, int lg, int lc) {
#pragma unroll
  for (int ks = 0; ks < 2; ++ks) {
    int kb = ks * 32 + lg * 8;
    bf16x8 af[8], bff[4];
#pragma unroll
    for (int i = 0; i < 8; ++i) af[i] = frag_read(A, wm * 128 + i * 16 + lc, kb);
#pragma unroll
    for (int i = 0; i < 4; ++i) bff[i] = frag_read(B, wn * 64 + i * 16 + lc, kb);
#pragma unroll
    for (int mf = 0; mf < 8; ++mf)
#pragma unroll
      for (int nf = 0; nf < 4; ++nf)
        acc[mf][nf] = mfma16(af[mf], bff[nf], acc[mf][nf]);
  }
}
// gemm1: 8 waves (2Mx4N), per-wave 128x32 (acc 8x2)
DEV void mfma256x128(const unsigned short* A, const unsigned short* B,
                     f32x4 (&acc)[8][2], int wm, int wn, int lg, int lc) {
#pragma unroll
  for (int ks = 0; ks < 2; ++ks) {
    int kb = ks * 32 + lg * 8;
    bf16x8 af[8], bff[2];
#pragma unroll
    for (int i = 0; i < 8; ++i) af[i] = frag_read(A, wm * 128 + i * 16 + lc, kb);
#pragma unroll
    for (int i = 0; i < 2; ++i) bff[i] = frag_read(B, wn * 32 + i * 16 + lc, kb);
#pragma unroll
    for (int mf = 0; mf < 8; ++mf)
#pragma unroll
      for (int nf = 0; nf < 2; ++nf)
        acc[mf][nf] = mfma16(af[mf], bff[nf], acc[mf][nf]);
  }
}

// ---------------------------------------------------------------------------

__global__ __launch_bounds__(256) void k_cast_x(const float* __restrict__ x,
    unsigned short* __restrict__ xh, unsigned short* __restrict__ xl) {
  int stride = gridDim.x * blockDim.x;
  for (int i = blockIdx.x * blockDim.x + threadIdx.x; i < 8192 * 1024 / 4;
       i += stride) {
    float4 v = ((const float4*)x)[i];
    ushort4 h, l;
    h.x = f2bf(v.x); l.x = f2bf(v.x - bf2f(h.x));
    h.y = f2bf(v.y); l.y = f2bf(v.y - bf2f(h.y));
    h.z = f2bf(v.z); l.z = f2bf(v.z - bf2f(h.z));
    h.w = f2bf(v.w); l.w = f2bf(v.w - bf2f(h.w));
    ((ushort4*)xh)[i] = h;
    ((ushort4*)xl)[i] = l;
  }
}

__global__ void k_zero(int* cnt, float* probsum) {
  int t = threadIdx.x;
  if (t < 16) cnt[t] = 0;
  if (t < 8)  probsum[t] = 0.f;
}

// Transpose fp32 [E][K][N] -> bf16 [E][N][K] via 64x64 LDS tiles.
__global__ __launch_bounds__(256) void k_transp(const float* __restrict__ src,
    unsigned short* __restrict__ dst, int K, int N) {
  int ntn = N >> 6;
  int kt = blockIdx.x / ntn, nt = blockIdx.x % ntn;
  int e = blockIdx.y;
  __shared__ float tl[64][65];
  const float* s = src + (size_t)e * K * N;
  unsigned short* d = dst + (size_t)e * N * K;
  int tid = threadIdx.x;
  int c4 = (tid & 15) * 4, rr = tid >> 4;
#pragma unroll
  for (int p = 0; p < 4; ++p) {
    int row = rr + p * 16;
    float4 v = *(const float4*)(s + (size_t)(kt * 64 + row) * N + nt * 64 + c4);
    tl[row][c4] = v.x; tl[row][c4 + 1] = v.y;
    tl[row][c4 + 2] = v.z; tl[row][c4 + 3] = v.w;
  }
  __syncthreads();
#pragma unroll
  for (int p = 0; p < 4; ++p) {
    int n = rr + p * 16;
    ushort4 o;
    o.x = f2bf(tl[c4 + 0][n]); o.y = f2bf(tl[c4 + 1][n]);
    o.z = f2bf(tl[c4 + 2][n]); o.w = f2bf(tl[c4 + 3][n]);
    *(ushort4*)(d + (size_t)(nt * 64 + n) * K + kt * 64 + c4) = o;
  }
}

// Same transpose but emits hi/lo bf16 split (for w_route).
__global__ __launch_bounds__(256) void k_transp_split(const float* __restrict__ src,
    unsigned short* __restrict__ dh, unsigned short* __restrict__ dl, int K, int N) {
  int ntn = N >> 6;
  int kt = blockIdx.x / ntn, nt = blockIdx.x % ntn;
  int e = blockIdx.y;
  __shared__ float tl[64][65];
  const float* s = src + (size_t)e * K * N;
  size_t dbase = (size_t)e * N * K;
  int tid = threadIdx.x;
  int c4 = (tid & 15) * 4, rr = tid >> 4;
#pragma unroll
  for (int p = 0; p < 4; ++p) {
    int row = rr + p * 16;
    float4 v = *(const float4*)(s + (size_t)(kt * 64 + row) * N + nt * 64 + c4);
    tl[row][c4] = v.x; tl[row][c4 + 1] = v.y;
    tl[row][c4 + 2] = v.z; tl[row][c4 + 3] = v.w;
  }
  __syncthreads();
#pragma unroll
  for (int p = 0; p < 4; ++p) {
    int n = rr + p * 16;
    ushort4 oh, ol;
#pragma unroll
    for (int i = 0; i < 4; ++i) {
      float v = tl[c4 + i][n];
      unsigned short hh = f2bf(v);
      unsigned short ll = f2bf(v - bf2f(hh));
      ((unsigned short*)&oh)[i] = hh;
      ((unsigned short*)&ol)[i] = ll;
    }
    *(ushort4*)(dh + dbase + (size_t)(nt * 64 + n) * K + kt * 64 + c4) = oh;
    *(ushort4*)(dl + dbase + (size_t)(nt * 64 + n) * K + kt * 64 + c4) = ol;
  }
}

// Routing GEMM: acts[n, e*128+r] = x . w_route, 3-term bf16 split; fp32 norms.
__global__ __launch_bounds__(256) void k_route_gemm(
    const unsigned short* __restrict__ xh, const unsigned short* __restrict__ xl,
    const unsigned short* __restrict__ wrh_t, const unsigned short* __restrict__ wrl_t,
    unsigned short* __restrict__ acts, float* __restrict__ norms_out) {
  __shared__ __align__(16) unsigned short Ah[128 * 64], Al[128 * 64];
  __shared__ __align__(16) unsigned short Bh[128 * 64], Bl[128 * 64];
  __shared__ float ssq_s[128][2];
  int tid = threadIdx.x;
  int mt = blockIdx.x, e = blockIdx.y;
  int wq = tid >> 6, lane = tid & 63;
  int wm = wq >> 1, wn = wq & 1, lg = lane >> 4, lc = lane & 15;
  f32x4 acc[4][4] = {};
  const unsigned short* ah_src = xh + (size_t)mt * 128 * 1024;
  const unsigned short* al_src = xl + (size_t)mt * 128 * 1024;
  const unsigned short* bh_src = wrh_t + (size_t)e * 128 * 1024;
  const unsigned short* bl_src = wrl_t + (size_t)e * 128 * 1024;
  for (int kt = 0; kt < 16; ++kt) {
    int k0 = kt * 64;
    stage_linear(ah_src, 1024, k0, Ah, tid);
    stage_linear(al_src, 1024, k0, Al, tid);
    stage_linear(bh_src, 1024, k0, Bh, tid);
    stage_linear(bl_src, 1024, k0, Bl, tid);
    __syncthreads();
#pragma unroll
    for (int ks = 0; ks < 2; ++ks) {
      int kb = ks * 32 + lg * 8;
      bf16x8 ahf[4], alf[4], bhf[4], blf[4];
#pragma unroll
      for (int i = 0; i < 4; ++i) {
        ahf[i] = frag_read(Ah, wm * 64 + i * 16 + lc, kb);
        alf[i] = frag_read(Al, wm * 64 + i * 16 + lc, kb);
        bhf[i] = frag_read(Bh, wn * 64 + i * 16 + lc, kb);
        blf[i] = frag_read(Bl, wn * 64 + i * 16 + lc, kb);
      }
#pragma unroll
      for (int mf = 0; mf < 4; ++mf)
#pragma unroll
        for (int nf = 0; nf < 4; ++nf) {
          acc[mf][nf] = mfma16(ahf[mf], bhf[nf], acc[mf][nf]);
          acc[mf][nf] = mfma16(alf[mf], bhf[nf], acc[mf][nf]);
          acc[mf][nf] = mfma16(ahf[mf], blf[nf], acc[mf][nf]);
        }
    }
    __syncthreads();
  }
  float ssq[4][4];
#pragma unroll
  for (int mf = 0; mf < 4; ++mf)
#pragma unroll
    for (int r = 0; r < 4; ++r) ssq[mf][r] = 0.f;
#pragma unroll
  for (int mf = 0; mf < 4; ++mf)
#pragma unroll
    for (int nf = 0; nf < 4; ++nf)
#pragma unroll
      for (int r = 0; r < 4; ++r) {
        float v = acc[mf][nf][r];
        int row = wm * 64 + mf * 16 + lg * 4 + r;
        int col = wn * 64 + nf * 16 + lc;
        acts[(size_t)(mt * 128 + row) * 1024 + e * 128 + col] = f2bf(v);
        ssq[mf][r] += v * v;
      }
#pragma unroll
  for (int mf = 0; mf < 4; ++mf)
#pragma unroll
    for (int r = 0; r < 4; ++r) {
      float s = ssq[mf][r];
      s += __shfl_xor(s, 1); s += __shfl_xor(s, 2);
      s += __shfl_xor(s, 4); s += __shfl_xor(s, 8);
      if (lc == 0) ssq_s[wm * 64 + mf * 16 + lg * 4 + r][wn] = s;
    }
  __syncthreads();
  if (tid < 128) {
    float s = ssq_s[tid][0] + ssq_s[tid][1];
    norms_out[(size_t)(mt * 128 + tid) * 8 + e] = sqrtf(s);
  }
}

// Per-token softmax + top-2.
__global__ __launch_bounds__(256) void k_router(const float* __restrict__ norms,
    float* __restrict__ topw, int* __restrict__ sel,
    int* __restrict__ cnt, float* __restrict__ probsum) {
  __shared__ float ps_s[8];
  __shared__ int cnt_s[16];
  int tid = threadIdx.x;
  if (tid < 8)  ps_s[tid] = 0.f;
  if (tid < 16) cnt_s[tid] = 0;
  __syncthreads();
  int n = blockIdx.x * 256 + tid;
  float p[8], mx = -3.4e38f;
#pragma unroll
  for (int e = 0; e < 8; ++e) { p[e] = norms[(size_t)n * 8 + e]; mx = fmaxf(mx, p[e]); }
  float s = 0.f;
#pragma unroll
  for (int e = 0; e < 8; ++e) { p[e] = __expf(p[e] - mx); s += p[e]; }
  float inv = 1.f / s;
  int i1 = 0; float v1 = p[0];
#pragma unroll
  for (int e = 1; e < 8; ++e) if (p[e] > v1) { v1 = p[e]; i1 = e; }
  int i2 = -1; float v2 = -1.f;
#pragma unroll
  for (int e = 0; e < 8; ++e) if (e != i1 && p[e] > v2) { v2 = p[e]; i2 = e; }
  float wsum = v1 + v2;
  topw[n * 2 + 0] = v1 / wsum;
  topw[n * 2 + 1] = v2 / wsum;
  sel[n * 2 + 0] = i1;
  sel[n * 2 + 1] = i2;
  atomicAdd(&cnt_s[i1], 1);
  atomicAdd(&cnt_s[8 + i2], 1);
#pragma unroll
  for (int e = 0; e < 8; ++e) atomicAdd(&ps_s[e], p[e] * inv);
  __syncthreads();
  if (tid < 8)  atomicAdd(&probsum[tid], ps_s[tid]);
  if (tid < 16) atomicAdd(&cnt[tid], cnt_s[tid]);
}

// Planner: combined 256-row tile map (<=80 entries, both slots), bl_loss.
__global__ void k_plan(const int* __restrict__ cnt, const float* __restrict__ probsum,
                       int* __restrict__ offs, int* __restrict__ fill,
                       int4* __restrict__ tilemap, float* __restrict__ bl_out) {
  int t = 0;
  for (int k = 0; k < 2; ++k) {
    int pos = 0;
    for (int e = 0; e < 8; ++e) {
      int c = cnt[k * 8 + e];
      offs[k * 8 + e] = pos;
      int ntl = (c + 255) >> 8;
      for (int i = 0; i < ntl; ++i) {
        int rr = c - i * 256; if (rr > 256) rr = 256;
        tilemap[t] = make_int4(e, k * 8192 + pos + i * 256, rr, 0);
        ++t;
      }
      pos += c;
    }
  }
  for (; t < 80; ++t) tilemap[t] = make_int4(0, 0, 0, 0);
  for (int i = 0; i < 16; ++i) fill[i] = 0;
  float bl = 0.f;
  for (int e = 0; e < 8; ++e)
    bl += ((float)(cnt[e] + cnt[8 + e]) / 8192.f) * (probsum[e] / 8192.f);
  *bl_out = bl * 8.f;
}

__global__ __launch_bounds__(256) void k_fill(const int* __restrict__ sel,
    const float* __restrict__ topw, const int* __restrict__ offs,
    int* __restrict__ fill, int* __restrict__ list01, float* __restrict__ wlist) {
  int n = blockIdx.x * 256 + threadIdx.x;
#pragma unroll
  for (int k = 0; k < 2; ++k) {
    int e = sel[n * 2 + k];
    int pos = atomicAdd(&fill[k * 8 + e], 1);
    int idx = k * 8192 + offs[k * 8 + e] + pos;
    list01[idx] = n;
    wlist[idx] = topw[n * 2 + k];
  }
}

// GEMM1: h = (x@w3[e]) * silu(acts[:,e,:]@wr2h[e]); 256x128 tile, 2-phase.
__global__ __launch_bounds__(512, 2) void k_gemm1(
    const unsigned short* __restrict__ xh, const unsigned short* __restrict__ acts,
    const unsigned short* __restrict__ w3t, const unsigned short* __restrict__ wr2h_t,
    const int* __restrict__ list, const int4* __restrict__ tilemap, int tile_lo,
    int nt, unsigned short* __restrict__ hbuf) {
  __shared__ __align__(16) unsigned short SA[2][256 * 64];
  __shared__ __align__(16) unsigned short SB[2][128 * 64];
  __shared__ int toks[256];
  int wg = xcd_swz_gen((int)blockIdx.x, nt * 32);
  int tloc = wg >> 5, bn = wg & 31;
  int4 ent = tilemap[tile_lo + tloc];
  int e = ent.x, posbase = ent.y, rows = ent.z;
  if (rows == 0) return;
  int tid = threadIdx.x;
  if (tid < 256) {
    int rr = tid < rows ? tid : rows - 1;
    toks[tid] = list[posbase + rr];
  }
  __syncthreads();
  int wq = tid >> 6, lane = tid & 63;
  int wm = wq >> 2, wn = wq & 3, lg = lane >> 4, lc = lane & 15;
  f32x4 acc_a[8][2] = {}, acc_s[8][2] = {};
  const unsigned short* bsrc  = w3t + ((size_t)e * 4096 + bn * 128) * 1024;
  const unsigned short* b2src = wr2h_t + ((size_t)e * 4096 + bn * 128) * 128;
  stage_g256(xh, 1024, 0, 0, toks, SA[0], tid);
  stage_l128(bsrc, 1024, 0, SB[0], tid);
  __syncthreads();
  int cur = 0;
  for (int kt = 0; kt < 15; ++kt) {
    stage_g256(xh, 1024, 0, (kt + 1) * 64, toks, SA[cur ^ 1], tid);
    stage_l128(bsrc, 1024, (kt + 1) * 64, SB[cur ^ 1], tid);
    mfma256x128(SA[cur], SB[cur], acc_a, wm, wn, lg, lc);
    __syncthreads();
    cur ^= 1;
  }
  // last main K-tile; prefetch acts K-tile 0
  stage_g256(acts, 1024, (size_t)e * 128, 0, toks, SA[cur ^ 1], tid);
  stage_l128(b2src, 128, 0, SB[cur ^ 1], tid);
  mfma256x128(SA[cur], SB[cur], acc_a, wm, wn, lg, lc);
  __syncthreads();
  cur ^= 1;
  stage_g256(acts, 1024, (size_t)e * 128, 64, toks, SA[cur ^ 1], tid);
  stage_l128(b2src, 128, 64, SB[cur ^ 1], tid);
  mfma256x128(SA[cur], SB[cur], acc_s, wm, wn, lg, lc);
  __syncthreads();
  cur ^= 1;
  mfma256x128(SA[cur], SB[cur], acc_s, wm, wn, lg, lc);
  size_t hrow0 = (size_t)tloc * 256;
#pragma unroll
  for (int mf = 0; mf < 8; ++mf)
#pragma unroll
    for (int nf = 0; nf < 2; ++nf)
#pragma unroll
      for (int r = 0; r < 4; ++r) {
        int row = wm * 128 + mf * 16 + lg * 4 + r;
        if (row < rows) {
          int col = wn * 32 + nf * 16 + lc;
          float sv = acc_s[mf][nf][r];
          float hv = acc_a[mf][nf][r] * (sv / (1.f + __expf(-sv)));
          hbuf[(hrow0 + row) * 4096 + (size_t)bn * 128 + col] = f2bf(hv);
        }
      }
}

// GEMM2: out[token, :] += (h @ wh2d[e]) * w; 256x256 tile, 2-phase, atomicAdd.
__global__ __launch_bounds__(512, 2) void k_gemm2(
    const unsigned short* __restrict__ hbuf, const unsigned short* __restrict__ wh2dt,
    const int* __restrict__ list, const float* __restrict__ wlist,
    const int4* __restrict__ tilemap, int tile_lo, int nt,
    float* __restrict__ out) {
  __shared__ __align__(16) unsigned short SA[2][256 * 64];
  __shared__ __align__(16) unsigned short SB[2][256 * 64];
  __shared__ int toks[256];
  __shared__ float wr_s[256];
  int wg = xcd_swz_gen((int)blockIdx.x, nt * 4);
  int tloc = wg >> 2, bn = wg & 3;
  int4 ent = tilemap[tile_lo + tloc];
  int e = ent.x, posbase = ent.y, rows = ent.z;
  if (rows == 0) return;
  int tid = threadIdx.x;
  if (tid < 256) {
    int rr = tid < rows ? tid : rows - 1;
    int t = list[posbase + rr];
    toks[tid] = t;
    wr_s[tid] = wlist[posbase + rr];
  }
  __syncthreads();
  int wq = tid >> 6, lane = tid & 63;
  int wm = wq >> 2, wn = wq & 3, lg = lane >> 4, lc = lane & 15;
  f32x4 acc[8][4] = {};
  const unsigned short* asrc = hbuf + (size_t)tloc * 256 * 4096;
  const unsigned short* bsrc = wh2dt + ((size_t)e * 1024 + bn * 256) * 4096;
  stage_l256(asrc, 4096, 0, SA[0], tid);
  stage_l256(bsrc, 4096, 0, SB[0], tid);
  __syncthreads();
  int cur = 0;
  for (int kt = 0; kt < 63; ++kt) {
    stage_l256(asrc, 4096, (kt + 1) * 64, SA[cur ^ 1], tid);
    stage_l256(bsrc, 4096, (kt + 1) * 64, SB[cur ^ 1], tid);
    mfma256x256(SA[cur], SB[cur], acc, wm, wn, lg, lc);
    __syncthreads();
    cur ^= 1;
  }
  mfma256x256(SA[cur], SB[cur], acc, wm, wn, lg, lc);
#pragma unroll
  for (int mf = 0; mf < 8; ++mf)
#pragma unroll
    for (int nf = 0; nf < 4; ++nf)
#pragma unroll
      for (int r = 0; r < 4; ++r) {
        int row = wm * 128 + mf * 16 + lg * 4 + r;
        if (row < rows) {
          int col = wn * 64 + nf * 16 + lc;
          float v = acc[mf][nf][r] * wr_s[row];
          atomicAdd(out + (size_t)toks[row] * 1024 + bn * 256 + col, v);
        }
      }
}

// ---------------------------------------------------------------------------

extern "C" void kernel_launch(void* const* d_in, const int* in_sizes, int n_in,
                              void* d_out, int out_size, void* d_ws, size_t ws_size,
                              hipStream_t stream) {
  (void)in_sizes; (void)n_in; (void)out_size;
  const float* x      = (const float*)d_in[0];
  const float* wroute = (const float*)d_in[1];
  const float* w3     = (const float*)d_in[2];
  const float* wr2h   = (const float*)d_in[3];
  const float* wh2d   = (const float*)d_in[4];
  float* out = (float*)d_out;

  char* ws = (char*)d_ws;
  size_t off = 0;
  auto carve = [&](size_t bytes) -> void* {
    void* p = ws + off; off += (bytes + 255) & ~(size_t)255; return p;
  };
  unsigned short* xh     = (unsigned short*)carve((size_t)8192 * 1024 * 2);
  unsigned short* xl     = (unsigned short*)carve((size_t)8192 * 1024 * 2);
  unsigned short* wrh_t  = (unsigned short*)carve((size_t)8 * 128 * 1024 * 2);
  unsigned short* wrl_t  = (unsigned short*)carve((size_t)8 * 128 * 1024 * 2);
  unsigned short* w3t    = (unsigned short*)carve((size_t)8 * 4096 * 1024 * 2);
  unsigned short* wr2h_t = (unsigned short*)carve((size_t)8 * 4096 * 128 * 2);
  unsigned short* wh2dt  = (unsigned short*)carve((size_t)8 * 1024 * 4096 * 2);
  unsigned short* acts   = (unsigned short*)carve((size_t)8192 * 1024 * 2);
  int*   list01 = (int*)carve(2 * 8192 * 4);
  float* wlist  = (float*)carve(2 * 8192 * 4);
  int*   sel    = (int*)carve(8192 * 2 * 4);
  float* topw   = (float*)carve(8192 * 2 * 4);
  int*   ctr    = (int*)carve(8192);
  int* cnt = ctr; int* fill = ctr + 16; int* offs = ctr + 32;
  float* probsum = (float*)(ctr + 48);
  int4* tilemap = (int4*)(ctr + 64);

  // h buffer: tiles-per-chunk sized to remaining scratch (2 MiB per tile).
  size_t avail = ws_size > off ? ws_size - off : 0;
  int tpc = 0;
  const int cands[4] = {80, 40, 20, 10};
  for (int i = 0; i < 4; ++i) {
    if ((size_t)cands[i] * 256 * 4096 * 2 <= avail) { tpc = cands[i]; break; }
  }
  if (!tpc) return;
  unsigned short* hbuf = (unsigned short*)(ws + off);

  float* norms_out = out + 8388608;   // [N, E] fp32
  float* bl_out    = out + 8454144;   // scalar

  hipMemsetAsync(out, 0, (size_t)8388608 * 4, stream);
  k_cast_x<<<2048, 256, 0, stream>>>(x, xh, xl);
  k_zero<<<1, 64, 0, stream>>>(cnt, probsum);
  k_transp<<<dim3(16 * 64, 8), 256, 0, stream>>>(w3, w3t, 1024, 4096);
  k_transp<<<dim3(64 * 16, 8), 256, 0, stream>>>(wh2d, wh2dt, 4096, 1024);
  k_transp<<<dim3(2 * 64, 8), 256, 0, stream>>>(wr2h, wr2h_t, 128, 4096);
  k_transp_split<<<dim3(16 * 2, 8), 256, 0, stream>>>(wroute, wrh_t, wrl_t, 1024, 128);
  k_route_gemm<<<dim3(64, 8), 256, 0, stream>>>(xh, xl, wrh_t, wrl_t, acts, norms_out);
  k_router<<<32, 256, 0, stream>>>(norms_out, topw, sel, cnt, probsum);
  k_plan<<<1, 1, 0, stream>>>(cnt, probsum, offs, fill, tilemap, bl_out);
  k_fill<<<32, 256, 0, stream>>>(sel, topw, offs, fill, list01, wlist);

  int nchunk = (80 + tpc - 1) / tpc;
  for (int c = 0; c < nchunk; ++c) {
    int tile_lo = c * tpc;
    int nt = 80 - tile_lo < tpc ? 80 - tile_lo : tpc;
    k_gemm1<<<nt * 32, 512, 0, stream>>>(
        xh, acts, w3t, wr2h_t, list01, tilemap, tile_lo, nt, hbuf);
    k_gemm2<<<nt * 4, 512, 0, stream>>>(
        hbuf, wh2dt, list01, wlist, tilemap, tile_lo, nt, out);
  }
}

// Round 4
// 859.101 us; speedup vs baseline: 1.1117x; 1.1117x over previous
//
#include <hip/hip_runtime.h>

// ---------------------------------------------------------------------------
// Routed top-2 MoE for MI355X (gfx950).  Round 4:
//  - gemm1/gemm2 rebuilt on a 3-deep circular-LDS software pipeline:
//    BK=32 K-tiles, stage t+2 while computing t, counted s_waitcnt vmcnt(3)
//    once per K-tile (never 0 in steady state), raw s_barrier (x2/K-tile),
//    setprio(1) around the 16-MFMA cluster  (T3+T4+T5 per learn_hip).
//  - gemm1: 256 tokens x 128 h-cols, 8 waves 4Mx2N, dual acc (fused silu
//    gate as 4 extra pipeline K-tiles).  gemm2: 128 tokens x 256 d-cols,
//    8 waves 2Mx4N, 128-row tile map derived from the 256-row map.
//  - BK=32 pair-of-rows XOR LDS swizzle (2-way bank, free) with linear
//    global_load_lds dest + inverse-swizzled per-thread source pointers.
// ---------------------------------------------------------------------------

#define DEV static __device__ __forceinline__

typedef float  f32x4  __attribute__((ext_vector_type(4)));
typedef __bf16 bf16x8 __attribute__((ext_vector_type(8)));

#define VMCNT_(n) asm volatile("s_waitcnt vmcnt(" #n ")" ::: "memory")
#define VMCNT(n) VMCNT_(n)
#define SBAR()   asm volatile("s_barrier" ::: "memory")

DEV unsigned short f2bf(float f) {
  union { float f; unsigned u; } v; v.f = f;
  unsigned r = v.u + 0x7fffu + ((v.u >> 16) & 1u);   // RNE
  return (unsigned short)(r >> 16);
}
DEV float bf2f(unsigned short b) {
  union { unsigned u; float f; } v; v.u = ((unsigned)b) << 16;
  return v.f;
}

DEV void gll16(const void* g, void* l) {
  __builtin_amdgcn_global_load_lds(
      (const __attribute__((address_space(1))) unsigned int*)g,
      (__attribute__((address_space(3))) unsigned int*)l, 16, 0, 0);
}

DEV f32x4 mfma16(bf16x8 a, bf16x8 b, f32x4 c) {
  return __builtin_amdgcn_mfma_f32_16x16x32_bf16(a, b, c, 0, 0, 0);
}

// Bijective XCD chunk swizzle (m204 general form).
DEV int xcd_swz_gen(int bid, int nwg) {
  int x = bid & 7, o = bid >> 3;
  int q = nwg >> 3, r = nwg & 7;
  return (x < r ? x * (q + 1) : r * (q + 1) + (x - r) * q) + o;
}

// ---- BK=32 tile layout ----------------------------------------------------
// Tile [R][32] bf16, 16B slots; physical slot s -> logical (row, b):
//   p = s>>3 (row pair), w0 = (s&7) ^ (p&7), row = 2p + (w0>>2), b = w0&3.
// Reader (row, kb=lg*8) -> byte (row>>1)*128 + ((((row&1)<<2)|lg)^(p&7))*16.
// 16-lane frag reads hit each bank exactly 2x (free).
DEV int swz_slot(int s) {               // -> row*4 + b
  int p = s >> 3, w0 = (s & 7) ^ (p & 7);
  return (((p << 1) | (w0 >> 2)) << 2) | (w0 & 3);
}
DEV bf16x8 frag_read32(const unsigned short* lds, int row, int lg) {
  int p = row >> 1;
  int off = p * 128 + (((((row & 1) << 2) | lg) ^ (p & 7)) << 4);
  return *(const bf16x8*)((const char*)lds + off);
}

// ---- BK=64 layout (route gemm, unchanged from r3) -------------------------
DEV bf16x8 frag_read(const unsigned short* lds, int row, int kb) {
  int off = row * 128 + ((kb * 2) ^ ((row & 7) << 4));
  return *(const bf16x8*)((const char*)lds + off);
}
DEV void stage_linear(const unsigned short* base, size_t pitch, int k0,
                      unsigned short* lds, int tid) {
  int wq = tid >> 6, lane = tid & 63;
#pragma unroll
  for (int i = 0; i < 4; ++i) {
    int s = wq * 256 + i * 64 + lane;
    int row = s >> 3, b = s & 7;
    int bb = b ^ (row & 7);
    const unsigned short* g = base + (size_t)row * pitch + (size_t)(k0 + bb * 8);
    gll16(g, lds + (size_t)(wq * 256 + i * 64) * 8);
  }
}
DEV void mfma_block(const unsigned short* A, const unsigned short* B,
                    f32x4 (&acc)[4][4], int wm, int wn, int lg, int lc) {
#pragma unroll
  for (int ks = 0; ks < 2; ++ks) {
    int kb = ks * 32 + lg * 8;
    bf16x8 af[4], bff[4];
#pragma unroll
    for (int i = 0; i < 4; ++i) {
      af[i]  = frag_read(A, wm * 64 + i * 16 + lc, kb);
      bff[i] = frag_read(B, wn * 64 + i * 16 + lc, kb);
    }
#pragma unroll
    for (int mf = 0; mf < 4; ++mf)
#pragma unroll
      for (int nf = 0; nf < 4; ++nf)
        acc[mf][nf] = mfma16(af[mf], bff[nf], acc[mf][nf]);
  }
}

// ---------------------------------------------------------------------------

__global__ __launch_bounds__(256) void k_cast_x(const float* __restrict__ x,
    unsigned short* __restrict__ xh, unsigned short* __restrict__ xl) {
  int stride = gridDim.x * blockDim.x;
  for (int i = blockIdx.x * blockDim.x + threadIdx.x; i < 8192 * 1024 / 4;
       i += stride) {
    float4 v = ((const float4*)x)[i];
    ushort4 h, l;
    h.x = f2bf(v.x); l.x = f2bf(v.x - bf2f(h.x));
    h.y = f2bf(v.y); l.y = f2bf(v.y - bf2f(h.y));
    h.z = f2bf(v.z); l.z = f2bf(v.z - bf2f(h.z));
    h.w = f2bf(v.w); l.w = f2bf(v.w - bf2f(h.w));
    ((ushort4*)xh)[i] = h;
    ((ushort4*)xl)[i] = l;
  }
}

__global__ void k_zero(int* cnt, float* probsum) {
  int t = threadIdx.x;
  if (t < 16) cnt[t] = 0;
  if (t < 8)  probsum[t] = 0.f;
}

// Transpose fp32 [E][K][N] -> bf16 [E][N][K] via 64x64 LDS tiles.
__global__ __launch_bounds__(256) void k_transp(const float* __restrict__ src,
    unsigned short* __restrict__ dst, int K, int N) {
  int ntn = N >> 6;
  int kt = blockIdx.x / ntn, nt = blockIdx.x % ntn;
  int e = blockIdx.y;
  __shared__ float tl[64][65];
  const float* s = src + (size_t)e * K * N;
  unsigned short* d = dst + (size_t)e * N * K;
  int tid = threadIdx.x;
  int c4 = (tid & 15) * 4, rr = tid >> 4;
#pragma unroll
  for (int p = 0; p < 4; ++p) {
    int row = rr + p * 16;
    float4 v = *(const float4*)(s + (size_t)(kt * 64 + row) * N + nt * 64 + c4);
    tl[row][c4] = v.x; tl[row][c4 + 1] = v.y;
    tl[row][c4 + 2] = v.z; tl[row][c4 + 3] = v.w;
  }
  __syncthreads();
#pragma unroll
  for (int p = 0; p < 4; ++p) {
    int n = rr + p * 16;
    ushort4 o;
    o.x = f2bf(tl[c4 + 0][n]); o.y = f2bf(tl[c4 + 1][n]);
    o.z = f2bf(tl[c4 + 2][n]); o.w = f2bf(tl[c4 + 3][n]);
    *(ushort4*)(d + (size_t)(nt * 64 + n) * K + kt * 64 + c4) = o;
  }
}

// Same transpose but emits hi/lo bf16 split (for w_route).
__global__ __launch_bounds__(256) void k_transp_split(const float* __restrict__ src,
    unsigned short* __restrict__ dh, unsigned short* __restrict__ dl, int K, int N) {
  int ntn = N >> 6;
  int kt = blockIdx.x / ntn, nt = blockIdx.x % ntn;
  int e = blockIdx.y;
  __shared__ float tl[64][65];
  const float* s = src + (size_t)e * K * N;
  size_t dbase = (size_t)e * N * K;
  int tid = threadIdx.x;
  int c4 = (tid & 15) * 4, rr = tid >> 4;
#pragma unroll
  for (int p = 0; p < 4; ++p) {
    int row = rr + p * 16;
    float4 v = *(const float4*)(s + (size_t)(kt * 64 + row) * N + nt * 64 + c4);
    tl[row][c4] = v.x; tl[row][c4 + 1] = v.y;
    tl[row][c4 + 2] = v.z; tl[row][c4 + 3] = v.w;
  }
  __syncthreads();
#pragma unroll
  for (int p = 0; p < 4; ++p) {
    int n = rr + p * 16;
    ushort4 oh, ol;
#pragma unroll
    for (int i = 0; i < 4; ++i) {
      float v = tl[c4 + i][n];
      unsigned short hh = f2bf(v);
      unsigned short ll = f2bf(v - bf2f(hh));
      ((unsigned short*)&oh)[i] = hh;
      ((unsigned short*)&ol)[i] = ll;
    }
    *(ushort4*)(dh + dbase + (size_t)(nt * 64 + n) * K + kt * 64 + c4) = oh;
    *(ushort4*)(dl + dbase + (size_t)(nt * 64 + n) * K + kt * 64 + c4) = ol;
  }
}

// Routing GEMM: acts[n, e*128+r] = x . w_route, 3-term bf16 split; fp32 norms.
__global__ __launch_bounds__(256) void k_route_gemm(
    const unsigned short* __restrict__ xh, const unsigned short* __restrict__ xl,
    const unsigned short* __restrict__ wrh_t, const unsigned short* __restrict__ wrl_t,
    unsigned short* __restrict__ acts, float* __restrict__ norms_out) {
  __shared__ __align__(16) unsigned short Ah[128 * 64], Al[128 * 64];
  __shared__ __align__(16) unsigned short Bh[128 * 64], Bl[128 * 64];
  __shared__ float ssq_s[128][2];
  int tid = threadIdx.x;
  int mt = blockIdx.x, e = blockIdx.y;
  int wq = tid >> 6, lane = tid & 63;
  int wm = wq >> 1, wn = wq & 1, lg = lane >> 4, lc = lane & 15;
  f32x4 acc[4][4] = {};
  const unsigned short* ah_src = xh + (size_t)mt * 128 * 1024;
  const unsigned short* al_src = xl + (size_t)mt * 128 * 1024;
  const unsigned short* bh_src = wrh_t + (size_t)e * 128 * 1024;
  const unsigned short* bl_src = wrl_t + (size_t)e * 128 * 1024;
  for (int kt = 0; kt < 16; ++kt) {
    int k0 = kt * 64;
    stage_linear(ah_src, 1024, k0, Ah, tid);
    stage_linear(al_src, 1024, k0, Al, tid);
    stage_linear(bh_src, 1024, k0, Bh, tid);
    stage_linear(bl_src, 1024, k0, Bl, tid);
    __syncthreads();
#pragma unroll
    for (int ks = 0; ks < 2; ++ks) {
      int kb = ks * 32 + lg * 8;
      bf16x8 ahf[4], alf[4], bhf[4], blf[4];
#pragma unroll
      for (int i = 0; i < 4; ++i) {
        ahf[i] = frag_read(Ah, wm * 64 + i * 16 + lc, kb);
        alf[i] = frag_read(Al, wm * 64 + i * 16 + lc, kb);
        bhf[i] = frag_read(Bh, wn * 64 + i * 16 + lc, kb);
        blf[i] = frag_read(Bl, wn * 64 + i * 16 + lc, kb);
      }
#pragma unroll
      for (int mf = 0; mf < 4; ++mf)
#pragma unroll
        for (int nf = 0; nf < 4; ++nf) {
          acc[mf][nf] = mfma16(ahf[mf], bhf[nf], acc[mf][nf]);
          acc[mf][nf] = mfma16(alf[mf], bhf[nf], acc[mf][nf]);
          acc[mf][nf] = mfma16(ahf[mf], blf[nf], acc[mf][nf]);
        }
    }
    __syncthreads();
  }
  float ssq[4][4];
#pragma unroll
  for (int mf = 0; mf < 4; ++mf)
#pragma unroll
    for (int r = 0; r < 4; ++r) ssq[mf][r] = 0.f;
#pragma unroll
  for (int mf = 0; mf < 4; ++mf)
#pragma unroll
    for (int nf = 0; nf < 4; ++nf)
#pragma unroll
      for (int r = 0; r < 4; ++r) {
        float v = acc[mf][nf][r];
        int row = wm * 64 + mf * 16 + lg * 4 + r;
        int col = wn * 64 + nf * 16 + lc;
        acts[(size_t)(mt * 128 + row) * 1024 + e * 128 + col] = f2bf(v);
        ssq[mf][r] += v * v;
      }
#pragma unroll
  for (int mf = 0; mf < 4; ++mf)
#pragma unroll
    for (int r = 0; r < 4; ++r) {
      float s = ssq[mf][r];
      s += __shfl_xor(s, 1); s += __shfl_xor(s, 2);
      s += __shfl_xor(s, 4); s += __shfl_xor(s, 8);
      if (lc == 0) ssq_s[wm * 64 + mf * 16 + lg * 4 + r][wn] = s;
    }
  __syncthreads();
  if (tid < 128) {
    float s = ssq_s[tid][0] + ssq_s[tid][1];
    norms_out[(size_t)(mt * 128 + tid) * 8 + e] = sqrtf(s);
  }
}

// Per-token softmax + top-2.
__global__ __launch_bounds__(256) void k_router(const float* __restrict__ norms,
    float* __restrict__ topw, int* __restrict__ sel,
    int* __restrict__ cnt, float* __restrict__ probsum) {
  __shared__ float ps_s[8];
  __shared__ int cnt_s[16];
  int tid = threadIdx.x;
  if (tid < 8)  ps_s[tid] = 0.f;
  if (tid < 16) cnt_s[tid] = 0;
  __syncthreads();
  int n = blockIdx.x * 256 + tid;
  float p[8], mx = -3.4e38f;
#pragma unroll
  for (int e = 0; e < 8; ++e) { p[e] = norms[(size_t)n * 8 + e]; mx = fmaxf(mx, p[e]); }
  float s = 0.f;
#pragma unroll
  for (int e = 0; e < 8; ++e) { p[e] = __expf(p[e] - mx); s += p[e]; }
  float inv = 1.f / s;
  int i1 = 0; float v1 = p[0];
#pragma unroll
  for (int e = 1; e < 8; ++e) if (p[e] > v1) { v1 = p[e]; i1 = e; }
  int i2 = -1; float v2 = -1.f;
#pragma unroll
  for (int e = 0; e < 8; ++e) if (e != i1 && p[e] > v2) { v2 = p[e]; i2 = e; }
  float wsum = v1 + v2;
  topw[n * 2 + 0] = v1 / wsum;
  topw[n * 2 + 1] = v2 / wsum;
  sel[n * 2 + 0] = i1;
  sel[n * 2 + 1] = i2;
  atomicAdd(&cnt_s[i1], 1);
  atomicAdd(&cnt_s[8 + i2], 1);
#pragma unroll
  for (int e = 0; e < 8; ++e) atomicAdd(&ps_s[e], p[e] * inv);
  __syncthreads();
  if (tid < 8)  atomicAdd(&probsum[tid], ps_s[tid]);
  if (tid < 16) atomicAdd(&cnt[tid], cnt_s[tid]);
}

// Planner: 256-row tile map (<=80) + derived 128-row map (<=160), bl_loss.
__global__ void k_plan(const int* __restrict__ cnt, const float* __restrict__ probsum,
                       int* __restrict__ offs, int* __restrict__ fill,
                       int4* __restrict__ tilemap, float* __restrict__ bl_out) {
  int4* map256 = tilemap;
  int4* map128 = tilemap + 80;
  int t = 0;
  for (int k = 0; k < 2; ++k) {
    int pos = 0;
    for (int e = 0; e < 8; ++e) {
      int c = cnt[k * 8 + e];
      offs[k * 8 + e] = pos;
      int ntl = (c + 255) >> 8;
      for (int i = 0; i < ntl; ++i) {
        int rr = c - i * 256; if (rr > 256) rr = 256;
        map256[t] = make_int4(e, k * 8192 + pos + i * 256, rr, 0);
        ++t;
      }
      pos += c;
    }
  }
  for (; t < 80; ++t) map256[t] = make_int4(0, 0, 0, 0);
  for (int i = 0; i < 80; ++i) {
    int4 m = map256[i];
    for (int h = 0; h < 2; ++h) {
      int r = m.z - h * 128;
      if (r < 0) r = 0; if (r > 128) r = 128;
      map128[i * 2 + h] = make_int4(m.x, m.y + h * 128, r, i * 256 + h * 128);
    }
  }
  for (int i = 0; i < 16; ++i) fill[i] = 0;
  float bl = 0.f;
  for (int e = 0; e < 8; ++e)
    bl += ((float)(cnt[e] + cnt[8 + e]) / 8192.f) * (probsum[e] / 8192.f);
  *bl_out = bl * 8.f;
}

__global__ __launch_bounds__(256) void k_fill(const int* __restrict__ sel,
    const float* __restrict__ topw, const int* __restrict__ offs,
    int* __restrict__ fill, int* __restrict__ list01, float* __restrict__ wlist) {
  int n = blockIdx.x * 256 + threadIdx.x;
#pragma unroll
  for (int k = 0; k < 2; ++k) {
    int e = sel[n * 2 + k];
    int pos = atomicAdd(&fill[k * 8 + e], 1);
    int idx = k * 8192 + offs[k * 8 + e] + pos;
    list01[idx] = n;
    wlist[idx] = topw[n * 2 + k];
  }
}

// ---------------------------------------------------------------------------
// GEMM1: h = (x@w3[e]) * silu(acts[:,e,:]@wr2h[e]).
// 256 tokens x 128 h-cols, BK=32, 3-deep pipeline, T = 32 main + 4 gate tiles.
// ---------------------------------------------------------------------------
__global__ __launch_bounds__(512, 2) void k_gemm1(
    const unsigned short* __restrict__ xh, const unsigned short* __restrict__ acts,
    const unsigned short* __restrict__ w3t, const unsigned short* __restrict__ wr2h_t,
    const int* __restrict__ list, const int4* __restrict__ tilemap, int tile_lo,
    int nt, unsigned short* __restrict__ hbuf) {
  __shared__ __align__(16) unsigned short SA[3][256 * 32];
  __shared__ __align__(16) unsigned short SB[3][128 * 32];
  __shared__ int toks[256];
  int wg = xcd_swz_gen((int)blockIdx.x, nt * 32);
  int tloc = wg >> 5, bn = wg & 31;
  int4 ent = tilemap[tile_lo + tloc];
  int e = ent.x, posbase = ent.y, rows = ent.z;
  if (rows == 0) return;
  int tid = threadIdx.x;
  if (tid < 256) {
    int rr = tid < rows ? tid : rows - 1;
    toks[tid] = list[posbase + rr];
  }
  __syncthreads();
  int wq = tid >> 6, lane = tid & 63;
  int wm = wq >> 1, wn = wq & 1, lg = lane >> 4, lc = lane & 15;
  // staging slots (linear LDS dest, inverse-swizzled source)
  int sA0 = wq * 128 + lane, sA1 = sA0 + 64;
  int sB0 = wq * 64 + lane;
  int vA0 = swz_slot(sA0), vA1 = swz_slot(sA1), vB0 = swz_slot(sB0);
  const unsigned short* gA0 = xh + (size_t)toks[vA0 >> 2] * 1024 + (vA0 & 3) * 8;
  const unsigned short* gA1 = xh + (size_t)toks[vA1 >> 2] * 1024 + (vA1 & 3) * 8;
  const unsigned short* qA0 = acts + (size_t)toks[vA0 >> 2] * 1024 + e * 128 + (vA0 & 3) * 8;
  const unsigned short* qA1 = acts + (size_t)toks[vA1 >> 2] * 1024 + e * 128 + (vA1 & 3) * 8;
  const unsigned short* gB0 =
      w3t + ((size_t)e * 4096 + bn * 128 + (vB0 >> 2)) * 1024 + (vB0 & 3) * 8;
  const unsigned short* qB0 =
      wr2h_t + ((size_t)e * 4096 + bn * 128 + (vB0 >> 2)) * 128 + (vB0 & 3) * 8;
  f32x4 acc_a[4][4] = {}, acc_s[4][4] = {};

  auto stage1 = [&](int tt, int bs) {
    unsigned short* dA0 = &SA[bs][(size_t)sA0 * 8];
    unsigned short* dA1 = &SA[bs][(size_t)sA1 * 8];
    unsigned short* dB0 = &SB[bs][(size_t)sB0 * 8];
    if (tt < 32) {
      int k0 = tt * 32;
      gll16(gA0 + k0, dA0); gll16(gA1 + k0, dA1); gll16(gB0 + k0, dB0);
    } else {
      int k0 = (tt - 32) * 32;
      gll16(qA0 + k0, dA0); gll16(qA1 + k0, dA1); gll16(qB0 + k0, dB0);
    }
  };

  stage1(0, 0); stage1(1, 1);
  int cur = 0, bs = 2;

#define G1_TILE(VMN, DO_STAGE, STT, ACC)                                     \
  {                                                                          \
    VMCNT(VMN); SBAR();                                                      \
    bf16x8 af[4], bf[4];                                                     \
    _Pragma("unroll") for (int i = 0; i < 4; ++i)                            \
      af[i] = frag_read32(&SA[cur][0], wm * 64 + i * 16 + lc, lg);           \
    _Pragma("unroll") for (int i = 0; i < 4; ++i)                            \
      bf[i] = frag_read32(&SB[cur][0], wn * 64 + i * 16 + lc, lg);           \
    if (DO_STAGE) stage1(STT, bs);                                           \
    SBAR();                                                                  \
    __builtin_amdgcn_s_setprio(1);                                           \
    _Pragma("unroll") for (int mf = 0; mf < 4; ++mf)                         \
      _Pragma("unroll") for (int nf = 0; nf < 4; ++nf)                       \
        ACC[mf][nf] = mfma16(af[mf], bf[nf], ACC[mf][nf]);                   \
    __builtin_amdgcn_s_setprio(0);                                           \
    cur = cur == 2 ? 0 : cur + 1;                                            \
    bs  = bs  == 2 ? 0 : bs  + 1;                                            \
  }

  for (int t = 0; t < 32; ++t) G1_TILE(3, true, t + 2, acc_a);
  G1_TILE(3, true, 34, acc_s);
  G1_TILE(3, true, 35, acc_s);
  G1_TILE(3, false, 0, acc_s);
  G1_TILE(0, false, 0, acc_s);
#undef G1_TILE

  size_t hrow0 = (size_t)tloc * 256;
#pragma unroll
  for (int mf = 0; mf < 4; ++mf)
#pragma unroll
    for (int nf = 0; nf < 4; ++nf)
#pragma unroll
      for (int r = 0; r < 4; ++r) {
        int row = wm * 64 + mf * 16 + lg * 4 + r;
        if (row < rows) {
          int col = wn * 64 + nf * 16 + lc;
          float sv = acc_s[mf][nf][r];
          float hv = acc_a[mf][nf][r] * (sv / (1.f + __expf(-sv)));
          hbuf[(hrow0 + row) * 4096 + (size_t)bn * 128 + col] = f2bf(hv);
        }
      }
}

// ---------------------------------------------------------------------------
// GEMM2: out[token, :] += (h @ wh2d[e]) * w.  128 tokens x 256 d-cols,
// BK=32, T=128 K-tiles, same 3-deep pipeline; fp32 atomicAdd epilogue.
// ---------------------------------------------------------------------------
__global__ __launch_bounds__(512, 2) void k_gemm2(
    const unsigned short* __restrict__ hbuf, const unsigned short* __restrict__ wh2dt,
    const int* __restrict__ list, const float* __restrict__ wlist,
    const int4* __restrict__ map128, int tile_lo, int nt,
    float* __restrict__ out) {
  __shared__ __align__(16) unsigned short SA[3][128 * 32];
  __shared__ __align__(16) unsigned short SB[3][256 * 32];
  __shared__ int toks[128];
  __shared__ float wr_s[128];
  int wg = xcd_swz_gen((int)blockIdx.x, nt * 8);
  int tloc = wg >> 2, bn = wg & 3;
  int4 ent = map128[tile_lo * 2 + tloc];
  int e = ent.x, posbase = ent.y, rows = ent.z;
  if (rows == 0) return;
  int hb = ent.w - tile_lo * 256;   // chunk-local hbuf row base
  int tid = threadIdx.x;
  if (tid < 128) {
    int rr = tid < rows ? tid : rows - 1;
    toks[tid] = list[posbase + rr];
    wr_s[tid] = wlist[posbase + rr];
  }
  __syncthreads();
  int wq = tid >> 6, lane = tid & 63;
  int wm = wq >> 2, wn = wq & 3, lg = lane >> 4, lc = lane & 15;
  int sA0 = wq * 64 + lane;
  int sB0 = wq * 128 + lane, sB1 = sB0 + 64;
  int vA0 = swz_slot(sA0), vB0 = swz_slot(sB0), vB1 = swz_slot(sB1);
  const unsigned short* gA0 = hbuf + (size_t)(hb + (vA0 >> 2)) * 4096 + (vA0 & 3) * 8;
  const unsigned short* gB0 =
      wh2dt + ((size_t)e * 1024 + bn * 256 + (vB0 >> 2)) * 4096 + (vB0 & 3) * 8;
  const unsigned short* gB1 =
      wh2dt + ((size_t)e * 1024 + bn * 256 + (vB1 >> 2)) * 4096 + (vB1 & 3) * 8;
  f32x4 acc[4][4] = {};

  auto stage2 = [&](int tt, int bs) {
    int k0 = tt * 32;
    gll16(gA0 + k0, &SA[bs][(size_t)sA0 * 8]);
    gll16(gB0 + k0, &SB[bs][(size_t)sB0 * 8]);
    gll16(gB1 + k0, &SB[bs][(size_t)sB1 * 8]);
  };

  stage2(0, 0); stage2(1, 1);
  int cur = 0, bs = 2;

#define G2_TILE(VMN, DO_STAGE, STT)                                          \
  {                                                                          \
    VMCNT(VMN); SBAR();                                                      \
    bf16x8 af[4], bf[4];                                                     \
    _Pragma("unroll") for (int i = 0; i < 4; ++i)                            \
      af[i] = frag_read32(&SA[cur][0], wm * 64 + i * 16 + lc, lg);           \
    _Pragma("unroll") for (int i = 0; i < 4; ++i)                            \
      bf[i] = frag_read32(&SB[cur][0], wn * 64 + i * 16 + lc, lg);           \
    if (DO_STAGE) stage2(STT, bs);                                           \
    SBAR();                                                                  \
    __builtin_amdgcn_s_setprio(1);                                           \
    _Pragma("unroll") for (int mf = 0; mf < 4; ++mf)                         \
      _Pragma("unroll") for (int nf = 0; nf < 4; ++nf)                       \
        acc[mf][nf] = mfma16(af[mf], bf[nf], acc[mf][nf]);                   \
    __builtin_amdgcn_s_setprio(0);                                           \
    cur = cur == 2 ? 0 : cur + 1;                                            \
    bs  = bs  == 2 ? 0 : bs  + 1;                                            \
  }

  for (int t = 0; t < 126; ++t) G2_TILE(3, true, t + 2);
  G2_TILE(3, false, 0);
  G2_TILE(0, false, 0);
#undef G2_TILE

#pragma unroll
  for (int mf = 0; mf < 4; ++mf)
#pragma unroll
    for (int nf = 0; nf < 4; ++nf)
#pragma unroll
      for (int r = 0; r < 4; ++r) {
        int row = wm * 64 + mf * 16 + lg * 4 + r;
        if (row < rows) {
          int col = wn * 64 + nf * 16 + lc;
          float v = acc[mf][nf][r] * wr_s[row];
          atomicAdd(out + (size_t)toks[row] * 1024 + bn * 256 + col, v);
        }
      }
}

// ---------------------------------------------------------------------------

extern "C" void kernel_launch(void* const* d_in, const int* in_sizes, int n_in,
                              void* d_out, int out_size, void* d_ws, size_t ws_size,
                              hipStream_t stream) {
  (void)in_sizes; (void)n_in; (void)out_size;
  const float* x      = (const float*)d_in[0];
  const float* wroute = (const float*)d_in[1];
  const float* w3     = (const float*)d_in[2];
  const float* wr2h   = (const float*)d_in[3];
  const float* wh2d   = (const float*)d_in[4];
  float* out = (float*)d_out;

  char* ws = (char*)d_ws;
  size_t off = 0;
  auto carve = [&](size_t bytes) -> void* {
    void* p = ws + off; off += (bytes + 255) & ~(size_t)255; return p;
  };
  unsigned short* xh     = (unsigned short*)carve((size_t)8192 * 1024 * 2);
  unsigned short* xl     = (unsigned short*)carve((size_t)8192 * 1024 * 2);
  unsigned short* wrh_t  = (unsigned short*)carve((size_t)8 * 128 * 1024 * 2);
  unsigned short* wrl_t  = (unsigned short*)carve((size_t)8 * 128 * 1024 * 2);
  unsigned short* w3t    = (unsigned short*)carve((size_t)8 * 4096 * 1024 * 2);
  unsigned short* wr2h_t = (unsigned short*)carve((size_t)8 * 4096 * 128 * 2);
  unsigned short* wh2dt  = (unsigned short*)carve((size_t)8 * 1024 * 4096 * 2);
  unsigned short* acts   = (unsigned short*)carve((size_t)8192 * 1024 * 2);
  int*   list01 = (int*)carve(2 * 8192 * 4);
  float* wlist  = (float*)carve(2 * 8192 * 4);
  int*   sel    = (int*)carve(8192 * 2 * 4);
  float* topw   = (float*)carve(8192 * 2 * 4);
  int*   ctr    = (int*)carve(8192);
  int* cnt = ctr; int* fill = ctr + 16; int* offs = ctr + 32;
  float* probsum = (float*)(ctr + 48);
  int4* tilemap = (int4*)(ctr + 64);    // 80 x map256 + 160 x map128

  size_t avail = ws_size > off ? ws_size - off : 0;
  int tpc = 0;
  const int cands[4] = {80, 40, 20, 10};
  for (int i = 0; i < 4; ++i) {
    if ((size_t)cands[i] * 256 * 4096 * 2 <= avail) { tpc = cands[i]; break; }
  }
  if (!tpc) return;
  unsigned short* hbuf = (unsigned short*)(ws + off);

  float* norms_out = out + 8388608;   // [N, E] fp32
  float* bl_out    = out + 8454144;   // scalar

  hipMemsetAsync(out, 0, (size_t)8388608 * 4, stream);
  k_cast_x<<<2048, 256, 0, stream>>>(x, xh, xl);
  k_zero<<<1, 64, 0, stream>>>(cnt, probsum);
  k_transp<<<dim3(16 * 64, 8), 256, 0, stream>>>(w3, w3t, 1024, 4096);
  k_transp<<<dim3(64 * 16, 8), 256, 0, stream>>>(wh2d, wh2dt, 4096, 1024);
  k_transp<<<dim3(2 * 64, 8), 256, 0, stream>>>(wr2h, wr2h_t, 128, 4096);
  k_transp_split<<<dim3(16 * 2, 8), 256, 0, stream>>>(wroute, wrh_t, wrl_t, 1024, 128);
  k_route_gemm<<<dim3(64, 8), 256, 0, stream>>>(xh, xl, wrh_t, wrl_t, acts, norms_out);
  k_router<<<32, 256, 0, stream>>>(norms_out, topw, sel, cnt, probsum);
  k_plan<<<1, 1, 0, stream>>>(cnt, probsum, offs, fill, tilemap, bl_out);
  k_fill<<<32, 256, 0, stream>>>(sel, topw, offs, fill, list01, wlist);

  int nchunk = (80 + tpc - 1) / tpc;
  for (int c = 0; c < nchunk; ++c) {
    int tile_lo = c * tpc;
    int nt = 80 - tile_lo < tpc ? 80 - tile_lo : tpc;
    k_gemm1<<<nt * 32, 512, 0, stream>>>(
        xh, acts, w3t, wr2h_t, list01, tilemap, tile_lo, nt, hbuf);
    k_gemm2<<<nt * 8, 512, 0, stream>>>(
        hbuf, wh2dt, list01, wlist, tilemap + 80, tile_lo, nt, out);
  }
}

// Round 5
// 843.959 us; speedup vs baseline: 1.1316x; 1.0179x over previous
//
#include <hip/hip_runtime.h>

// ---------------------------------------------------------------------------
// Routed top-2 MoE for MI355X (gfx950).  Round 5:
//  - gemm1/gemm2 ported to the m201 8-phase quadrant schedule (T2+T3+T4+T5):
//    BK=64 K-tiles, dbuf LDS, per-phase {quadrant ds_reads, 1 half-tile
//    global_load_lds stage, barrier, lgkmcnt(0), setprio(1), MFMA cluster,
//    setprio(0), barrier}; counted vmcnt(6)/(4) at phases 4 and 8 ONLY;
//    final iteration drains 4->2->0.  Stage targets the half-tile slot that
//    was consumed exactly one phase earlier (verified disjointness).
//  - gemm2: 256x256 (acc 32 frags), waves 2M(qm-split)x4N(qn-split).
//  - gemm1: 256x128 dual-acc (main + silu gate); gate K=128 = 2 extra
//    pipeline K-tiles sourced from acts/wr2h_t.
//  - zero-conflict XOR LDS swizzle kept (measured 0 conflicts r1-r4).
// ---------------------------------------------------------------------------

#define DEV static __device__ __forceinline__

typedef float  f32x4  __attribute__((ext_vector_type(4)));
typedef __bf16 bf16x8 __attribute__((ext_vector_type(8)));

#define VMCNT_(n) asm volatile("s_waitcnt vmcnt(" #n ")" ::: "memory")
#define VMCNT(n) VMCNT_(n)
#define LGKM0()  asm volatile("s_waitcnt lgkmcnt(0)" ::: "memory")

DEV unsigned short f2bf(float f) {
  union { float f; unsigned u; } v; v.f = f;
  unsigned r = v.u + 0x7fffu + ((v.u >> 16) & 1u);   // RNE
  return (unsigned short)(r >> 16);
}
DEV float bf2f(unsigned short b) {
  union { unsigned u; float f; } v; v.u = ((unsigned)b) << 16;
  return v.f;
}

DEV void gll16(const void* g, void* l) {
  __builtin_amdgcn_global_load_lds(
      (const __attribute__((address_space(1))) unsigned int*)g,
      (__attribute__((address_space(3))) unsigned int*)l, 16, 0, 0);
}

DEV f32x4 mfma16(bf16x8 a, bf16x8 b, f32x4 c) {
  return __builtin_amdgcn_mfma_f32_16x16x32_bf16(a, b, c, 0, 0, 0);
}

// Bijective XCD chunk swizzle (m204 general form).
DEV int xcd_swz_gen(int bid, int nwg) {
  int x = bid & 7, o = bid >> 3;
  int q = nwg >> 3, r = nwg & 7;
  return (x < r ? x * (q + 1) : r * (q + 1) + (x - r) * q) + o;
}

// Read one bf16x8 fragment (row, k-elem kb in [0,64)) from a swizzled
// [R][64] bf16 tile: byte = row*128 + ((kb*2) ^ ((row&7)<<4)).
DEV bf16x8 frag_read(const unsigned short* lds, int row, int kb) {
  int off = row * 128 + ((kb * 2) ^ ((row & 7) << 4));
  return *(const bf16x8*)((const char*)lds + off);
}

// ---- 256-thread staging (route gemm, unchanged) ---------------------------
DEV void stage_linear(const unsigned short* base, size_t pitch, int k0,
                      unsigned short* lds, int tid) {
  int wq = tid >> 6, lane = tid & 63;
#pragma unroll
  for (int i = 0; i < 4; ++i) {
    int s = wq * 256 + i * 64 + lane;
    int row = s >> 3, b = s & 7;
    int bb = b ^ (row & 7);
    const unsigned short* g = base + (size_t)row * pitch + (size_t)(k0 + bb * 8);
    gll16(g, lds + (size_t)(wq * 256 + i * 64) * 8);
  }
}
DEV void mfma_block(const unsigned short* A, const unsigned short* B,
                    f32x4 (&acc)[4][4], int wm, int wn, int lg, int lc) {
#pragma unroll
  for (int ks = 0; ks < 2; ++ks) {
    int kb = ks * 32 + lg * 8;
    bf16x8 af[4], bff[4];
#pragma unroll
    for (int i = 0; i < 4; ++i) {
      af[i]  = frag_read(A, wm * 64 + i * 16 + lc, kb);
      bff[i] = frag_read(B, wn * 64 + i * 16 + lc, kb);
    }
#pragma unroll
    for (int mf = 0; mf < 4; ++mf)
#pragma unroll
      for (int nf = 0; nf < 4; ++nf)
        acc[mf][nf] = mfma16(af[mf], bff[nf], acc[mf][nf]);
  }
}

// ---------------------------------------------------------------------------

__global__ __launch_bounds__(256) void k_cast_x(const float* __restrict__ x,
    unsigned short* __restrict__ xh, unsigned short* __restrict__ xl) {
  int stride = gridDim.x * blockDim.x;
  for (int i = blockIdx.x * blockDim.x + threadIdx.x; i < 8192 * 1024 / 4;
       i += stride) {
    float4 v = ((const float4*)x)[i];
    ushort4 h, l;
    h.x = f2bf(v.x); l.x = f2bf(v.x - bf2f(h.x));
    h.y = f2bf(v.y); l.y = f2bf(v.y - bf2f(h.y));
    h.z = f2bf(v.z); l.z = f2bf(v.z - bf2f(h.z));
    h.w = f2bf(v.w); l.w = f2bf(v.w - bf2f(h.w));
    ((ushort4*)xh)[i] = h;
    ((ushort4*)xl)[i] = l;
  }
}

__global__ void k_zero(int* cnt, float* probsum) {
  int t = threadIdx.x;
  if (t < 16) cnt[t] = 0;
  if (t < 8)  probsum[t] = 0.f;
}

// Transpose fp32 [E][K][N] -> bf16 [E][N][K] via 64x64 LDS tiles.
__global__ __launch_bounds__(256) void k_transp(const float* __restrict__ src,
    unsigned short* __restrict__ dst, int K, int N) {
  int ntn = N >> 6;
  int kt = blockIdx.x / ntn, nt = blockIdx.x % ntn;
  int e = blockIdx.y;
  __shared__ float tl[64][65];
  const float* s = src + (size_t)e * K * N;
  unsigned short* d = dst + (size_t)e * N * K;
  int tid = threadIdx.x;
  int c4 = (tid & 15) * 4, rr = tid >> 4;
#pragma unroll
  for (int p = 0; p < 4; ++p) {
    int row = rr + p * 16;
    float4 v = *(const float4*)(s + (size_t)(kt * 64 + row) * N + nt * 64 + c4);
    tl[row][c4] = v.x; tl[row][c4 + 1] = v.y;
    tl[row][c4 + 2] = v.z; tl[row][c4 + 3] = v.w;
  }
  __syncthreads();
#pragma unroll
  for (int p = 0; p < 4; ++p) {
    int n = rr + p * 16;
    ushort4 o;
    o.x = f2bf(tl[c4 + 0][n]); o.y = f2bf(tl[c4 + 1][n]);
    o.z = f2bf(tl[c4 + 2][n]); o.w = f2bf(tl[c4 + 3][n]);
    *(ushort4*)(d + (size_t)(nt * 64 + n) * K + kt * 64 + c4) = o;
  }
}

// Same transpose but emits hi/lo bf16 split (for w_route).
__global__ __launch_bounds__(256) void k_transp_split(const float* __restrict__ src,
    unsigned short* __restrict__ dh, unsigned short* __restrict__ dl, int K, int N) {
  int ntn = N >> 6;
  int kt = blockIdx.x / ntn, nt = blockIdx.x % ntn;
  int e = blockIdx.y;
  __shared__ float tl[64][65];
  const float* s = src + (size_t)e * K * N;
  size_t dbase = (size_t)e * N * K;
  int tid = threadIdx.x;
  int c4 = (tid & 15) * 4, rr = tid >> 4;
#pragma unroll
  for (int p = 0; p < 4; ++p) {
    int row = rr + p * 16;
    float4 v = *(const float4*)(s + (size_t)(kt * 64 + row) * N + nt * 64 + c4);
    tl[row][c4] = v.x; tl[row][c4 + 1] = v.y;
    tl[row][c4 + 2] = v.z; tl[row][c4 + 3] = v.w;
  }
  __syncthreads();
#pragma unroll
  for (int p = 0; p < 4; ++p) {
    int n = rr + p * 16;
    ushort4 oh, ol;
#pragma unroll
    for (int i = 0; i < 4; ++i) {
      float v = tl[c4 + i][n];
      unsigned short hh = f2bf(v);
      unsigned short ll = f2bf(v - bf2f(hh));
      ((unsigned short*)&oh)[i] = hh;
      ((unsigned short*)&ol)[i] = ll;
    }
    *(ushort4*)(dh + dbase + (size_t)(nt * 64 + n) * K + kt * 64 + c4) = oh;
    *(ushort4*)(dl + dbase + (size_t)(nt * 64 + n) * K + kt * 64 + c4) = ol;
  }
}

// Routing GEMM: acts[n, e*128+r] = x . w_route, 3-term bf16 split; fp32 norms.
__global__ __launch_bounds__(256) void k_route_gemm(
    const unsigned short* __restrict__ xh, const unsigned short* __restrict__ xl,
    const unsigned short* __restrict__ wrh_t, const unsigned short* __restrict__ wrl_t,
    unsigned short* __restrict__ acts, float* __restrict__ norms_out) {
  __shared__ __align__(16) unsigned short Ah[128 * 64], Al[128 * 64];
  __shared__ __align__(16) unsigned short Bh[128 * 64], Bl[128 * 64];
  __shared__ float ssq_s[128][2];
  int tid = threadIdx.x;
  int mt = blockIdx.x, e = blockIdx.y;
  int wq = tid >> 6, lane = tid & 63;
  int wm = wq >> 1, wn = wq & 1, lg = lane >> 4, lc = lane & 15;
  f32x4 acc[4][4] = {};
  const unsigned short* ah_src = xh + (size_t)mt * 128 * 1024;
  const unsigned short* al_src = xl + (size_t)mt * 128 * 1024;
  const unsigned short* bh_src = wrh_t + (size_t)e * 128 * 1024;
  const unsigned short* bl_src = wrl_t + (size_t)e * 128 * 1024;
  for (int kt = 0; kt < 16; ++kt) {
    int k0 = kt * 64;
    stage_linear(ah_src, 1024, k0, Ah, tid);
    stage_linear(al_src, 1024, k0, Al, tid);
    stage_linear(bh_src, 1024, k0, Bh, tid);
    stage_linear(bl_src, 1024, k0, Bl, tid);
    __syncthreads();
#pragma unroll
    for (int ks = 0; ks < 2; ++ks) {
      int kb = ks * 32 + lg * 8;
      bf16x8 ahf[4], alf[4], bhf[4], blf[4];
#pragma unroll
      for (int i = 0; i < 4; ++i) {
        ahf[i] = frag_read(Ah, wm * 64 + i * 16 + lc, kb);
        alf[i] = frag_read(Al, wm * 64 + i * 16 + lc, kb);
        bhf[i] = frag_read(Bh, wn * 64 + i * 16 + lc, kb);
        blf[i] = frag_read(Bl, wn * 64 + i * 16 + lc, kb);
      }
#pragma unroll
      for (int mf = 0; mf < 4; ++mf)
#pragma unroll
        for (int nf = 0; nf < 4; ++nf) {
          acc[mf][nf] = mfma16(ahf[mf], bhf[nf], acc[mf][nf]);
          acc[mf][nf] = mfma16(alf[mf], bhf[nf], acc[mf][nf]);
          acc[mf][nf] = mfma16(ahf[mf], blf[nf], acc[mf][nf]);
        }
    }
    __syncthreads();
  }
  float ssq[4][4];
#pragma unroll
  for (int mf = 0; mf < 4; ++mf)
#pragma unroll
    for (int r = 0; r < 4; ++r) ssq[mf][r] = 0.f;
#pragma unroll
  for (int mf = 0; mf < 4; ++mf)
#pragma unroll
    for (int nf = 0; nf < 4; ++nf)
#pragma unroll
      for (int r = 0; r < 4; ++r) {
        float v = acc[mf][nf][r];
        int row = wm * 64 + mf * 16 + lg * 4 + r;
        int col = wn * 64 + nf * 16 + lc;
        acts[(size_t)(mt * 128 + row) * 1024 + e * 128 + col] = f2bf(v);
        ssq[mf][r] += v * v;
      }
#pragma unroll
  for (int mf = 0; mf < 4; ++mf)
#pragma unroll
    for (int r = 0; r < 4; ++r) {
      float s = ssq[mf][r];
      s += __shfl_xor(s, 1); s += __shfl_xor(s, 2);
      s += __shfl_xor(s, 4); s += __shfl_xor(s, 8);
      if (lc == 0) ssq_s[wm * 64 + mf * 16 + lg * 4 + r][wn] = s;
    }
  __syncthreads();
  if (tid < 128) {
    float s = ssq_s[tid][0] + ssq_s[tid][1];
    norms_out[(size_t)(mt * 128 + tid) * 8 + e] = sqrtf(s);
  }
}

// Per-token softmax + top-2.
__global__ __launch_bounds__(256) void k_router(const float* __restrict__ norms,
    float* __restrict__ topw, int* __restrict__ sel,
    int* __restrict__ cnt, float* __restrict__ probsum) {
  __shared__ float ps_s[8];
  __shared__ int cnt_s[16];
  int tid = threadIdx.x;
  if (tid < 8)  ps_s[tid] = 0.f;
  if (tid < 16) cnt_s[tid] = 0;
  __syncthreads();
  int n = blockIdx.x * 256 + tid;
  float p[8], mx = -3.4e38f;
#pragma unroll
  for (int e = 0; e < 8; ++e) { p[e] = norms[(size_t)n * 8 + e]; mx = fmaxf(mx, p[e]); }
  float s = 0.f;
#pragma unroll
  for (int e = 0; e < 8; ++e) { p[e] = __expf(p[e] - mx); s += p[e]; }
  float inv = 1.f / s;
  int i1 = 0; float v1 = p[0];
#pragma unroll
  for (int e = 1; e < 8; ++e) if (p[e] > v1) { v1 = p[e]; i1 = e; }
  int i2 = -1; float v2 = -1.f;
#pragma unroll
  for (int e = 0; e < 8; ++e) if (e != i1 && p[e] > v2) { v2 = p[e]; i2 = e; }
  float wsum = v1 + v2;
  topw[n * 2 + 0] = v1 / wsum;
  topw[n * 2 + 1] = v2 / wsum;
  sel[n * 2 + 0] = i1;
  sel[n * 2 + 1] = i2;
  atomicAdd(&cnt_s[i1], 1);
  atomicAdd(&cnt_s[8 + i2], 1);
#pragma unroll
  for (int e = 0; e < 8; ++e) atomicAdd(&ps_s[e], p[e] * inv);
  __syncthreads();
  if (tid < 8)  atomicAdd(&probsum[tid], ps_s[tid]);
  if (tid < 16) atomicAdd(&cnt[tid], cnt_s[tid]);
}

// Planner: combined 256-row tile map (<=80 entries, both slots), bl_loss.
__global__ void k_plan(const int* __restrict__ cnt, const float* __restrict__ probsum,
                       int* __restrict__ offs, int* __restrict__ fill,
                       int4* __restrict__ tilemap, float* __restrict__ bl_out) {
  int t = 0;
  for (int k = 0; k < 2; ++k) {
    int pos = 0;
    for (int e = 0; e < 8; ++e) {
      int c = cnt[k * 8 + e];
      offs[k * 8 + e] = pos;
      int ntl = (c + 255) >> 8;
      for (int i = 0; i < ntl; ++i) {
        int rr = c - i * 256; if (rr > 256) rr = 256;
        tilemap[t] = make_int4(e, k * 8192 + pos + i * 256, rr, 0);
        ++t;
      }
      pos += c;
    }
  }
  for (; t < 80; ++t) tilemap[t] = make_int4(0, 0, 0, 0);
  for (int i = 0; i < 16; ++i) fill[i] = 0;
  float bl = 0.f;
  for (int e = 0; e < 8; ++e)
    bl += ((float)(cnt[e] + cnt[8 + e]) / 8192.f) * (probsum[e] / 8192.f);
  *bl_out = bl * 8.f;
}

__global__ __launch_bounds__(256) void k_fill(const int* __restrict__ sel,
    const float* __restrict__ topw, const int* __restrict__ offs,
    int* __restrict__ fill, int* __restrict__ list01, float* __restrict__ wlist) {
  int n = blockIdx.x * 256 + threadIdx.x;
#pragma unroll
  for (int k = 0; k < 2; ++k) {
    int e = sel[n * 2 + k];
    int pos = atomicAdd(&fill[k * 8 + e], 1);
    int idx = k * 8192 + offs[k * 8 + e] + pos;
    list01[idx] = n;
    wlist[idx] = topw[n * 2 + k];
  }
}

// ---------------------------------------------------------------------------
// GEMM1: h = (x@w3[e]) * silu(acts[:,e,:]@wr2h[e]).
// 256 tokens x 128 h-cols, 8 waves (2M x 4N), quadrant 8-phase schedule,
// T = 16 main + 2 gate K-tiles.  LDS: 2 x (32K A + 16K B) = 96 KiB.
// ---------------------------------------------------------------------------
__global__ __launch_bounds__(512, 2) void k_gemm1(
    const unsigned short* __restrict__ xh, const unsigned short* __restrict__ acts,
    const unsigned short* __restrict__ w3t, const unsigned short* __restrict__ wr2h_t,
    const int* __restrict__ list, const int4* __restrict__ tilemap, int tile_lo,
    int nt, unsigned short* __restrict__ hbuf) {
  __shared__ __align__(16) unsigned short SA[2][256 * 64];
  __shared__ __align__(16) unsigned short SB[2][128 * 64];
  __shared__ int toks[256];
  int wg = xcd_swz_gen((int)blockIdx.x, nt * 32);
  int tloc = wg >> 5, bn = wg & 31;
  int4 ent = tilemap[tile_lo + tloc];
  int e = ent.x, posbase = ent.y, rows = ent.z;
  if (rows == 0) return;
  int tid = threadIdx.x;
  if (tid < 256) {
    int rr = tid < rows ? tid : rows - 1;
    toks[tid] = list[posbase + rr];
  }
  __syncthreads();
  int wq = tid >> 6, lane = tid & 63;
  int wm = wq >> 2, wn = wq & 3, lg = lane >> 4, lc = lane & 15;

  // ---- staging precompute (linear LDS dest, inverse-swizzled source) ----
  int sa0 = tid, sa1 = tid + 512;
  int ra0 = sa0 >> 3, ra1 = sa1 >> 3;               // 0..63 / 64..127
  int ca0 = ((sa0 & 7) ^ (ra0 & 7)) * 8;
  int ca1 = ((sa1 & 7) ^ (ra1 & 7)) * 8;
  int tA00 = toks[ra0],      tA01 = toks[128 + ra0];
  int tA10 = toks[ra1],      tA11 = toks[128 + ra1];
  int rb = tid >> 3;                                 // 0..63
  int cb = ((tid & 7) ^ (rb & 7)) * 8;

  auto stageA = [&](int t, int h, int bi) {
    unsigned short* d0 = &SA[bi][(size_t)(h * 1024 + sa0) * 8];
    unsigned short* d1 = &SA[bi][(size_t)(h * 1024 + sa1) * 8];
    int t0 = h ? tA01 : tA00, t1 = h ? tA11 : tA10;
    if (t < 16) {
      int k0 = t * 64;
      gll16(xh + (size_t)t0 * 1024 + k0 + ca0, d0);
      gll16(xh + (size_t)t1 * 1024 + k0 + ca1, d1);
    } else {
      int k0 = e * 128 + (t - 16) * 64;
      gll16(acts + (size_t)t0 * 1024 + k0 + ca0, d0);
      gll16(acts + (size_t)t1 * 1024 + k0 + ca1, d1);
    }
  };
  auto stageB = [&](int t, int h, int bi) {
    unsigned short* d = &SB[bi][(size_t)(h * 512 + tid) * 8];
    if (t < 16) {
      gll16(w3t + ((size_t)e * 4096 + bn * 128 + h * 64 + rb) * 1024 + t * 64 + cb, d);
    } else {
      gll16(wr2h_t + ((size_t)e * 4096 + bn * 128 + h * 64 + rb) * 128 +
                (t - 16) * 64 + cb, d);
    }
  };

  f32x4 accm[2][4][2] = {}, accg[2][4][2] = {};
  bf16x8 af[4][2], bf[2][2];

#define G1_RA(BI, QM)                                                        \
  _Pragma("unroll") for (int mf = 0; mf < 4; ++mf)                           \
  _Pragma("unroll") for (int ks = 0; ks < 2; ++ks)                           \
    af[mf][ks] = frag_read(SA[BI], QM * 128 + wm * 64 + mf * 16 + lc,        \
                           ks * 32 + lg * 8);
#define G1_RB(BI, QN)                                                        \
  _Pragma("unroll") for (int ks = 0; ks < 2; ++ks)                           \
    bf[QN][ks] = frag_read(SB[BI], QN * 64 + wn * 16 + lc, ks * 32 + lg * 8);
#define G1_MMA(ACC, QM, QN)                                                  \
  __builtin_amdgcn_s_barrier();                                              \
  LGKM0();                                                                   \
  __builtin_amdgcn_s_setprio(1);                                             \
  _Pragma("unroll") for (int mf = 0; mf < 4; ++mf)                           \
  _Pragma("unroll") for (int ks = 0; ks < 2; ++ks)                           \
    ACC[QM][mf][QN] = mfma16(af[mf][ks], bf[QN][ks], ACC[QM][mf][QN]);       \
  __builtin_amdgcn_s_setprio(0);                                             \
  __builtin_amdgcn_s_barrier();

  // prologue: tile0 full + tile1 {Ah0,Bh0,Bh1}; wait tile0 landed.
  stageA(0, 0, 0); stageB(0, 0, 0); stageB(0, 1, 0); stageA(0, 1, 0);
  stageA(1, 0, 1); stageB(1, 0, 1); stageB(1, 1, 1);
  VMCNT(4);
  __builtin_amdgcn_s_barrier();

  for (int it = 0; it < 8; ++it) {
    int t0 = 2 * it;
    // p1 (t0: qm0,qn0)
    G1_RA(0, 0); G1_RB(0, 0);
    stageA(t0 + 1, 1, 1);
    G1_MMA(accm, 0, 0);
    // p2 (t0: qm0,qn1)
    G1_RB(0, 1);
    stageA(t0 + 2, 0, 0);
    G1_MMA(accm, 0, 1);
    // p3 (t0: qm1,qn1)
    G1_RA(0, 1);
    stageB(t0 + 2, 0, 0);
    G1_MMA(accm, 1, 1);
    // p4 (t0: qm1,qn0) — counted wait
    stageB(t0 + 2, 1, 0);
    VMCNT(4);
    G1_MMA(accm, 1, 0);
    // p5 (t1: qm0,qn0)
    G1_RA(1, 0); G1_RB(1, 0);
    stageA(t0 + 2, 1, 0);
    G1_MMA(accm, 0, 0);
    // p6 (t1: qm0,qn1)
    G1_RB(1, 1);
    stageA(t0 + 3, 0, 1);
    G1_MMA(accm, 0, 1);
    // p7 (t1: qm1,qn1)
    G1_RA(1, 1);
    stageB(t0 + 3, 0, 1);
    G1_MMA(accm, 1, 1);
    // p8 (t1: qm1,qn0) — counted wait
    stageB(t0 + 3, 1, 1);
    VMCNT(4);
    G1_MMA(accm, 1, 0);
  }
  // final iteration: tiles 16,17 (gate) -> accg; drain 3->2->0.
  {
    G1_RA(0, 0); G1_RB(0, 0);
    stageA(17, 1, 1);
    G1_MMA(accg, 0, 0);
    G1_RB(0, 1);
    G1_MMA(accg, 0, 1);
    G1_RA(0, 1);
    G1_MMA(accg, 1, 1);
    VMCNT(3);
    G1_MMA(accg, 1, 0);
    G1_RA(1, 0); G1_RB(1, 0);
    VMCNT(2);
    G1_MMA(accg, 0, 0);
    G1_RB(1, 1);
    VMCNT(0);
    G1_MMA(accg, 0, 1);
    G1_RA(1, 1);
    G1_MMA(accg, 1, 1);
    G1_MMA(accg, 1, 0);
  }
#undef G1_RA
#undef G1_RB
#undef G1_MMA

  size_t hrow0 = (size_t)tloc * 256;
#pragma unroll
  for (int qm = 0; qm < 2; ++qm)
#pragma unroll
    for (int mf = 0; mf < 4; ++mf)
#pragma unroll
      for (int qn = 0; qn < 2; ++qn)
#pragma unroll
        for (int r = 0; r < 4; ++r) {
          int row = qm * 128 + wm * 64 + mf * 16 + lg * 4 + r;
          if (row < rows) {
            int col = qn * 64 + wn * 16 + lc;
            float sv = accg[qm][mf][qn][r];
            float hv = accm[qm][mf][qn][r] * (sv / (1.f + __expf(-sv)));
            hbuf[(hrow0 + row) * 4096 + (size_t)bn * 128 + col] = f2bf(hv);
          }
        }
}

// ---------------------------------------------------------------------------
// GEMM2: out[token, :] += (h @ wh2d[e]) * w.  256 tokens x 256 d-cols,
// 8 waves (2M x 4N), quadrant 8-phase schedule, T = 64 K-tiles.
// LDS: 2 x (32K + 32K) = 128 KiB.  fp32 atomicAdd epilogue.
// ---------------------------------------------------------------------------
__global__ __launch_bounds__(512, 2) void k_gemm2(
    const unsigned short* __restrict__ hbuf, const unsigned short* __restrict__ wh2dt,
    const int* __restrict__ list, const float* __restrict__ wlist,
    const int4* __restrict__ tilemap, int tile_lo, int nt,
    float* __restrict__ out) {
  __shared__ __align__(16) unsigned short SA[2][256 * 64];
  __shared__ __align__(16) unsigned short SB[2][256 * 64];
  __shared__ int toks[256];
  __shared__ float wr_s[256];
  int wg = xcd_swz_gen((int)blockIdx.x, nt * 4);
  int tloc = wg >> 2, bn = wg & 3;
  int4 ent = tilemap[tile_lo + tloc];
  int e = ent.x, posbase = ent.y, rows = ent.z;
  if (rows == 0) return;
  int tid = threadIdx.x;
  if (tid < 256) {
    int rr = tid < rows ? tid : rows - 1;
    toks[tid] = list[posbase + rr];
    wr_s[tid] = wlist[posbase + rr];
  }
  __syncthreads();
  int wq = tid >> 6, lane = tid & 63;
  int wm = wq >> 2, wn = wq & 3, lg = lane >> 4, lc = lane & 15;

  int sa0 = tid, sa1 = tid + 512;
  int ra0 = sa0 >> 3, ra1 = sa1 >> 3;
  int ca0 = ((sa0 & 7) ^ (ra0 & 7)) * 8;
  int ca1 = ((sa1 & 7) ^ (ra1 & 7)) * 8;
  const unsigned short* abase = hbuf + (size_t)tloc * 256 * 4096;
  const unsigned short* bbase = wh2dt + ((size_t)e * 1024 + bn * 256) * 4096;

  auto stageA = [&](int t, int h, int bi) {
    gll16(abase + (size_t)(h * 128 + ra0) * 4096 + t * 64 + ca0,
          &SA[bi][(size_t)(h * 1024 + sa0) * 8]);
    gll16(abase + (size_t)(h * 128 + ra1) * 4096 + t * 64 + ca1,
          &SA[bi][(size_t)(h * 1024 + sa1) * 8]);
  };
  auto stageB = [&](int t, int h, int bi) {
    gll16(bbase + (size_t)(h * 128 + ra0) * 4096 + t * 64 + ca0,
          &SB[bi][(size_t)(h * 1024 + sa0) * 8]);
    gll16(bbase + (size_t)(h * 128 + ra1) * 4096 + t * 64 + ca1,
          &SB[bi][(size_t)(h * 1024 + sa1) * 8]);
  };

  f32x4 acc[2][4][2][2] = {};
  bf16x8 af[4][2], bf[2][2][2];

#define G2_RA(BI, QM)                                                        \
  _Pragma("unroll") for (int mf = 0; mf < 4; ++mf)                           \
  _Pragma("unroll") for (int ks = 0; ks < 2; ++ks)                           \
    af[mf][ks] = frag_read(SA[BI], QM * 128 + wm * 64 + mf * 16 + lc,        \
                           ks * 32 + lg * 8);
#define G2_RB(BI, QN)                                                        \
  _Pragma("unroll") for (int nf = 0; nf < 2; ++nf)                           \
  _Pragma("unroll") for (int ks = 0; ks < 2; ++ks)                           \
    bf[QN][nf][ks] = frag_read(SB[BI], QN * 128 + wn * 32 + nf * 16 + lc,    \
                               ks * 32 + lg * 8);
#define G2_MMA(QM, QN)                                                       \
  __builtin_amdgcn_s_barrier();                                              \
  LGKM0();                                                                   \
  __builtin_amdgcn_s_setprio(1);                                             \
  _Pragma("unroll") for (int mf = 0; mf < 4; ++mf)                           \
  _Pragma("unroll") for (int nf = 0; nf < 2; ++nf)                           \
  _Pragma("unroll") for (int ks = 0; ks < 2; ++ks)                           \
    acc[QM][mf][QN][nf] =                                                    \
        mfma16(af[mf][ks], bf[QN][nf][ks], acc[QM][mf][QN][nf]);             \
  __builtin_amdgcn_s_setprio(0);                                             \
  __builtin_amdgcn_s_barrier();

  stageA(0, 0, 0); stageB(0, 0, 0); stageB(0, 1, 0); stageA(0, 1, 0);
  stageA(1, 0, 1); stageB(1, 0, 1); stageB(1, 1, 1);
  VMCNT(6);
  __builtin_amdgcn_s_barrier();

  for (int it = 0; it < 31; ++it) {
    int t0 = 2 * it;
    G2_RA(0, 0); G2_RB(0, 0);
    stageA(t0 + 1, 1, 1);
    G2_MMA(0, 0);
    G2_RB(0, 1);
    stageA(t0 + 2, 0, 0);
    G2_MMA(0, 1);
    G2_RA(0, 1);
    stageB(t0 + 2, 0, 0);
    G2_MMA(1, 1);
    stageB(t0 + 2, 1, 0);
    VMCNT(6);
    G2_MMA(1, 0);
    G2_RA(1, 0); G2_RB(1, 0);
    stageA(t0 + 2, 1, 0);
    G2_MMA(0, 0);
    G2_RB(1, 1);
    stageA(t0 + 3, 0, 1);
    G2_MMA(0, 1);
    G2_RA(1, 1);
    stageB(t0 + 3, 0, 1);
    G2_MMA(1, 1);
    stageB(t0 + 3, 1, 1);
    VMCNT(6);
    G2_MMA(1, 0);
  }
  // final iteration (tiles 62,63): drain 4->2->0.
  {
    G2_RA(0, 0); G2_RB(0, 0);
    stageA(63, 1, 1);
    G2_MMA(0, 0);
    G2_RB(0, 1);
    G2_MMA(0, 1);
    G2_RA(0, 1);
    G2_MMA(1, 1);
    VMCNT(4);
    G2_MMA(1, 0);
    G2_RA(1, 0); G2_RB(1, 0);
    VMCNT(2);
    G2_MMA(0, 0);
    G2_RB(1, 1);
    VMCNT(0);
    G2_MMA(0, 1);
    G2_RA(1, 1);
    G2_MMA(1, 1);
    G2_MMA(1, 0);
  }
#undef G2_RA
#undef G2_RB
#undef G2_MMA

#pragma unroll
  for (int qm = 0; qm < 2; ++qm)
#pragma unroll
    for (int mf = 0; mf < 4; ++mf)
#pragma unroll
      for (int qn = 0; qn < 2; ++qn)
#pragma unroll
        for (int nf = 0; nf < 2; ++nf)
#pragma unroll
          for (int r = 0; r < 4; ++r) {
            int row = qm * 128 + wm * 64 + mf * 16 + lg * 4 + r;
            if (row < rows) {
              int col = qn * 128 + wn * 32 + nf * 16 + lc;
              float v = acc[qm][mf][qn][nf][r] * wr_s[row];
              atomicAdd(out + (size_t)toks[row] * 1024 + bn * 256 + col, v);
            }
          }
}

// ---------------------------------------------------------------------------

extern "C" void kernel_launch(void* const* d_in, const int* in_sizes, int n_in,
                              void* d_out, int out_size, void* d_ws, size_t ws_size,
                              hipStream_t stream) {
  (void)in_sizes; (void)n_in; (void)out_size;
  const float* x      = (const float*)d_in[0];
  const float* wroute = (const float*)d_in[1];
  const float* w3     = (const float*)d_in[2];
  const float* wr2h   = (const float*)d_in[3];
  const float* wh2d   = (const float*)d_in[4];
  float* out = (float*)d_out;

  char* ws = (char*)d_ws;
  size_t off = 0;
  auto carve = [&](size_t bytes) -> void* {
    void* p = ws + off; off += (bytes + 255) & ~(size_t)255; return p;
  };
  unsigned short* xh     = (unsigned short*)carve((size_t)8192 * 1024 * 2);
  unsigned short* xl     = (unsigned short*)carve((size_t)8192 * 1024 * 2);
  unsigned short* wrh_t  = (unsigned short*)carve((size_t)8 * 128 * 1024 * 2);
  unsigned short* wrl_t  = (unsigned short*)carve((size_t)8 * 128 * 1024 * 2);
  unsigned short* w3t    = (unsigned short*)carve((size_t)8 * 4096 * 1024 * 2);
  unsigned short* wr2h_t = (unsigned short*)carve((size_t)8 * 4096 * 128 * 2);
  unsigned short* wh2dt  = (unsigned short*)carve((size_t)8 * 1024 * 4096 * 2);
  unsigned short* acts   = (unsigned short*)carve((size_t)8192 * 1024 * 2);
  int*   list01 = (int*)carve(2 * 8192 * 4);
  float* wlist  = (float*)carve(2 * 8192 * 4);
  int*   sel    = (int*)carve(8192 * 2 * 4);
  float* topw   = (float*)carve(8192 * 2 * 4);
  int*   ctr    = (int*)carve(8192);
  int* cnt = ctr; int* fill = ctr + 16; int* offs = ctr + 32;
  float* probsum = (float*)(ctr + 48);
  int4* tilemap = (int4*)(ctr + 64);

  size_t avail = ws_size > off ? ws_size - off : 0;
  int tpc = 0;
  const int cands[4] = {80, 40, 20, 10};
  for (int i = 0; i < 4; ++i) {
    if ((size_t)cands[i] * 256 * 4096 * 2 <= avail) { tpc = cands[i]; break; }
  }
  if (!tpc) return;
  unsigned short* hbuf = (unsigned short*)(ws + off);

  float* norms_out = out + 8388608;   // [N, E] fp32
  float* bl_out    = out + 8454144;   // scalar

  hipMemsetAsync(out, 0, (size_t)8388608 * 4, stream);
  k_cast_x<<<2048, 256, 0, stream>>>(x, xh, xl);
  k_zero<<<1, 64, 0, stream>>>(cnt, probsum);
  k_transp<<<dim3(16 * 64, 8), 256, 0, stream>>>(w3, w3t, 1024, 4096);
  k_transp<<<dim3(64 * 16, 8), 256, 0, stream>>>(wh2d, wh2dt, 4096, 1024);
  k_transp<<<dim3(2 * 64, 8), 256, 0, stream>>>(wr2h, wr2h_t, 128, 4096);
  k_transp_split<<<dim3(16 * 2, 8), 256, 0, stream>>>(wroute, wrh_t, wrl_t, 1024, 128);
  k_route_gemm<<<dim3(64, 8), 256, 0, stream>>>(xh, xl, wrh_t, wrl_t, acts, norms_out);
  k_router<<<32, 256, 0, stream>>>(norms_out, topw, sel, cnt, probsum);
  k_plan<<<1, 1, 0, stream>>>(cnt, probsum, offs, fill, tilemap, bl_out);
  k_fill<<<32, 256, 0, stream>>>(sel, topw, offs, fill, list01, wlist);

  int nchunk = (80 + tpc - 1) / tpc;
  for (int c = 0; c < nchunk; ++c) {
    int tile_lo = c * tpc;
    int nt = 80 - tile_lo < tpc ? 80 - tile_lo : tpc;
    k_gemm1<<<nt * 32, 512, 0, stream>>>(
        xh, acts, w3t, wr2h_t, list01, tilemap, tile_lo, nt, hbuf);
    k_gemm2<<<nt * 4, 512, 0, stream>>>(
        hbuf, wh2dt, list01, wlist, tilemap, tile_lo, nt, out);
  }
}